// Round 1
// baseline (33.760 us; speedup 1.0000x reference)
//
#include <hip/hip_runtime.h>

// FutureEncoder: for each (b,t), attend over the next K=16 rows.
// out[b,t,:] = sum_j softmax_j(dot(x[b,t], x[b,t+1+j])) * x[b,t+1+j], j valid iff t+1+j < S.
//
// Strategy: one 64-lane wave handles TPW consecutive t's with a single pass
// over the union of their window rows (TPW-1+K rows), maintaining an online
// softmax state (m, s, acc) per t. Each row is loaded once per wave -> L2
// traffic ~ (TPW+K-1)/TPW rows per output row. fp32 throughout.

namespace {
constexpr int kB  = 2;
constexpr int kS  = 4096;
constexpr int kH  = 1024;
constexpr int kK  = 16;
constexpr int kTPW = 2;                 // t's per wave
constexpr int kFR = kH / (64 * 4);      // float4 fragments per lane per row = 4
}

__device__ __forceinline__ float wave_reduce_sum(float v) {
#pragma unroll
  for (int off = 32; off >= 1; off >>= 1)
    v += __shfl_xor(v, off, 64);
  return v;
}

__global__ __launch_bounds__(256)
void future_encoder_kernel(const float* __restrict__ x, float* __restrict__ out) {
  const int lane = (int)(threadIdx.x & 63);
  const int wave = (int)((blockIdx.x * blockDim.x + threadIdx.x) >> 6);
  const int t0g  = wave * kTPW;
  if (t0g >= kB * kS) return;
  const int b   = t0g / kS;
  const int tl0 = t0g % kS;             // kS % kTPW == 0, so a group never crosses batches
  const float* __restrict__ xb = x   + (size_t)b * kS * kH;
  float* __restrict__       ob = out + (size_t)b * kS * kH;
  const int col = lane * 4;

  // Own-query fragments: lane holds elements {p*256 + lane*4 .. +3}, p=0..3
  float4 xt[kTPW][kFR];
#pragma unroll
  for (int tt = 0; tt < kTPW; ++tt) {
#pragma unroll
    for (int p = 0; p < kFR; ++p)
      xt[tt][p] = *(const float4*)(xb + (size_t)(tl0 + tt) * kH + p * 256 + col);
  }

  // Online-softmax state per t
  float m[kTPW], s[kTPW];
  float4 acc[kTPW][kFR];
#pragma unroll
  for (int tt = 0; tt < kTPW; ++tt) {
    m[tt] = -1e30f;
    s[tt] = 0.f;
#pragma unroll
    for (int p = 0; p < kFR; ++p) acc[tt][p] = make_float4(0.f, 0.f, 0.f, 0.f);
  }

  const int rBeg = tl0 + 1;
  const int rEnd = min(tl0 + kTPW - 1 + kK, kS - 1);  // inclusive

  for (int r = rBeg; r <= rEnd; ++r) {
    float4 w[kFR];
#pragma unroll
    for (int p = 0; p < kFR; ++p)
      w[p] = *(const float4*)(xb + (size_t)r * kH + p * 256 + col);

#pragma unroll
    for (int tt = 0; tt < kTPW; ++tt) {
      const int d = r - tl0 - tt;
      if (d >= 1 && d <= kK) {
        // dot(x[t], x[r]) across all 1024 elements
        float part = 0.f;
#pragma unroll
        for (int p = 0; p < kFR; ++p) {
          part = fmaf(xt[tt][p].x, w[p].x, part);
          part = fmaf(xt[tt][p].y, w[p].y, part);
          part = fmaf(xt[tt][p].z, w[p].z, part);
          part = fmaf(xt[tt][p].w, w[p].w, part);
        }
        const float sc = wave_reduce_sum(part);  // wave-uniform

        // Online softmax update (branch is wave-uniform: sc and m are uniform)
        if (sc <= m[tt]) {
          const float p2 = __expf(sc - m[tt]);
          s[tt] += p2;
#pragma unroll
          for (int p = 0; p < kFR; ++p) {
            acc[tt][p].x = fmaf(p2, w[p].x, acc[tt][p].x);
            acc[tt][p].y = fmaf(p2, w[p].y, acc[tt][p].y);
            acc[tt][p].z = fmaf(p2, w[p].z, acc[tt][p].z);
            acc[tt][p].w = fmaf(p2, w[p].w, acc[tt][p].w);
          }
        } else {
          const float r2 = __expf(m[tt] - sc);   // 0 on first valid row (m = -1e30)
          m[tt] = sc;
          s[tt] = fmaf(s[tt], r2, 1.f);
#pragma unroll
          for (int p = 0; p < kFR; ++p) {
            acc[tt][p].x = fmaf(acc[tt][p].x, r2, w[p].x);
            acc[tt][p].y = fmaf(acc[tt][p].y, r2, w[p].y);
            acc[tt][p].z = fmaf(acc[tt][p].z, r2, w[p].z);
            acc[tt][p].w = fmaf(acc[tt][p].w, r2, w[p].w);
          }
        }
      }
    }
  }

  // Epilogue: out = acc / s  (s==0 only for t==S-1 -> exact zeros, matching ref)
#pragma unroll
  for (int tt = 0; tt < kTPW; ++tt) {
    const float inv = (s[tt] > 0.f) ? (1.f / s[tt]) : 0.f;
#pragma unroll
    for (int p = 0; p < kFR; ++p) {
      float4 o;
      o.x = acc[tt][p].x * inv;
      o.y = acc[tt][p].y * inv;
      o.z = acc[tt][p].z * inv;
      o.w = acc[tt][p].w * inv;
      *(float4*)(ob + (size_t)(tl0 + tt) * kH + p * 256 + col) = o;
    }
  }
}

extern "C" void kernel_launch(void* const* d_in, const int* in_sizes, int n_in,
                              void* d_out, int out_size, void* d_ws, size_t ws_size,
                              hipStream_t stream) {
  const float* x = (const float*)d_in[0];
  float* out = (float*)d_out;
  constexpr int kWaves   = kB * kS / kTPW;          // 4096 waves
  constexpr int kThreads = 256;                      // 4 waves / block
  constexpr int kBlocks  = kWaves * 64 / kThreads;   // 1024 blocks
  hipLaunchKernelGGL(future_encoder_kernel, dim3(kBlocks), dim3(kThreads), 0, stream,
                     x, out);
}

// Round 2
// 31.438 us; speedup vs baseline: 1.0739x; 1.0739x over previous
//
#include <hip/hip_runtime.h>

// FutureEncoder: out[b,t,:] = sum_j softmax_j(dot(x[b,t], x[b,t+1+j])) * x[b,t+1+j],
// j in [0,16), valid iff t+1+j < S. fp32 throughout.
//
// Round 2: chunked rows (C=3) with BATCHED butterfly reductions. The previous
// version serialized {load -> dot -> 6-dep-shfl reduce -> update} per row; the
// 6-deep shuffle chain (~25-30cyc/step on the DS pipe) dominated the critical
// path. Now 6 independent reduction chains (2 t's x 3 rows) pipeline together,
// amortizing the shuffle latency ~3x. Memory traffic unchanged (each window
// row loaded once per wave; TPW=2 -> ~9.5 rows/t from L2/L3).

namespace {
constexpr int kB   = 2;
constexpr int kS   = 4096;
constexpr int kH   = 1024;
constexpr int kK   = 16;
constexpr int kTPW = 2;                 // t's per wave
constexpr int kC   = 3;                 // window rows per chunk
constexpr int kFR  = kH / (64 * 4);     // float4 fragments per lane per row = 4
constexpr int kNV  = kTPW * kC;         // scores per chunk = 6
}

__global__ __launch_bounds__(256, 3)
void future_encoder_kernel(const float* __restrict__ x, float* __restrict__ out) {
  const int lane = (int)(threadIdx.x & 63);
  const int wave = (int)((blockIdx.x * blockDim.x + threadIdx.x) >> 6);
  const int t0g  = wave * kTPW;
  if (t0g >= kB * kS) return;
  const int b   = t0g / kS;
  const int tl0 = t0g % kS;             // kS % kTPW == 0: group never crosses batches
  const float* __restrict__ xb = x   + (size_t)b * kS * kH;
  float* __restrict__       ob = out + (size_t)b * kS * kH;
  const int col = lane * 4;

  // Query fragments: lane holds elements {p*256 + lane*4 .. +3}
  float4 xt[kTPW][kFR];
#pragma unroll
  for (int tt = 0; tt < kTPW; ++tt)
#pragma unroll
    for (int p = 0; p < kFR; ++p)
      xt[tt][p] = *(const float4*)(xb + (size_t)(tl0 + tt) * kH + p * 256 + col);

  // Online-softmax state per t
  float m[kTPW], s[kTPW];
  float4 acc[kTPW][kFR];
#pragma unroll
  for (int tt = 0; tt < kTPW; ++tt) {
    m[tt] = -1e30f;
    s[tt] = 0.f;
#pragma unroll
    for (int p = 0; p < kFR; ++p) acc[tt][p] = make_float4(0.f, 0.f, 0.f, 0.f);
  }

  const int rBeg = tl0 + 1;
  const int rEnd = min(tl0 + kTPW - 1 + kK, kS - 1);  // inclusive

  for (int r0 = rBeg; r0 <= rEnd; r0 += kC) {
    // ---- load chunk (independent loads; clamped rows are masked at update) ----
    float4 w[kC][kFR];
#pragma unroll
    for (int i = 0; i < kC; ++i) {
      const int r = min(r0 + i, rEnd);
#pragma unroll
      for (int p = 0; p < kFR; ++p)
        w[i][p] = *(const float4*)(xb + (size_t)r * kH + p * 256 + col);
    }

    // ---- partial dots: 2 accumulators each to shorten the fma chain ----
    float sc[kNV];
#pragma unroll
    for (int tt = 0; tt < kTPW; ++tt)
#pragma unroll
      for (int i = 0; i < kC; ++i) {
        float a0 = 0.f, a1 = 0.f;
#pragma unroll
        for (int p = 0; p < kFR; ++p) {
          a0 = fmaf(xt[tt][p].x, w[i][p].x, a0);
          a1 = fmaf(xt[tt][p].y, w[i][p].y, a1);
          a0 = fmaf(xt[tt][p].z, w[i][p].z, a0);
          a1 = fmaf(xt[tt][p].w, w[i][p].w, a1);
        }
        sc[tt * kC + i] = a0 + a1;
      }

    // ---- batched butterfly: 6 independent chains pipeline per level ----
#pragma unroll
    for (int off = 32; off >= 1; off >>= 1) {
      float other[kNV];
#pragma unroll
      for (int v = 0; v < kNV; ++v) other[v] = __shfl_xor(sc[v], off, 64);
#pragma unroll
      for (int v = 0; v < kNV; ++v) sc[v] += other[v];
    }

    // ---- online updates (wave-uniform scores -> uniform branches) ----
#pragma unroll
    for (int tt = 0; tt < kTPW; ++tt)
#pragma unroll
      for (int i = 0; i < kC; ++i) {
        const int r = r0 + i;
        const int d = r - tl0 - tt;
        if (r <= rEnd && d >= 1 && d <= kK) {
          const float v = sc[tt * kC + i];
          if (v <= m[tt]) {
            const float p2 = __expf(v - m[tt]);
            s[tt] += p2;
#pragma unroll
            for (int p = 0; p < kFR; ++p) {
              acc[tt][p].x = fmaf(p2, w[i][p].x, acc[tt][p].x);
              acc[tt][p].y = fmaf(p2, w[i][p].y, acc[tt][p].y);
              acc[tt][p].z = fmaf(p2, w[i][p].z, acc[tt][p].z);
              acc[tt][p].w = fmaf(p2, w[i][p].w, acc[tt][p].w);
            }
          } else {
            const float r2 = __expf(m[tt] - v);   // 0 on first valid row
            m[tt] = v;
            s[tt] = fmaf(s[tt], r2, 1.f);
#pragma unroll
            for (int p = 0; p < kFR; ++p) {
              acc[tt][p].x = fmaf(acc[tt][p].x, r2, w[i][p].x);
              acc[tt][p].y = fmaf(acc[tt][p].y, r2, w[i][p].y);
              acc[tt][p].z = fmaf(acc[tt][p].z, r2, w[i][p].z);
              acc[tt][p].w = fmaf(acc[tt][p].w, r2, w[i][p].w);
            }
          }
        }
      }
  }

  // ---- epilogue: out = acc / s  (s==0 only for t==S-1 -> exact zeros) ----
#pragma unroll
  for (int tt = 0; tt < kTPW; ++tt) {
    const float inv = (s[tt] > 0.f) ? (1.f / s[tt]) : 0.f;
#pragma unroll
    for (int p = 0; p < kFR; ++p) {
      float4 o;
      o.x = acc[tt][p].x * inv;
      o.y = acc[tt][p].y * inv;
      o.z = acc[tt][p].z * inv;
      o.w = acc[tt][p].w * inv;
      *(float4*)(ob + (size_t)(tl0 + tt) * kH + p * 256 + col) = o;
    }
  }
}

extern "C" void kernel_launch(void* const* d_in, const int* in_sizes, int n_in,
                              void* d_out, int out_size, void* d_ws, size_t ws_size,
                              hipStream_t stream) {
  const float* x = (const float*)d_in[0];
  float* out = (float*)d_out;
  constexpr int kWaves   = kB * kS / kTPW;           // 4096 waves
  constexpr int kThreads = 256;                       // 4 waves / block
  constexpr int kBlocks  = kWaves * 64 / kThreads;    // 1024 blocks
  hipLaunchKernelGGL(future_encoder_kernel, dim3(kBlocks), dim3(kThreads), 0, stream,
                     x, out);
}